// Round 10
// baseline (53.478 us; speedup 1.0000x reference)
//
#include <hip/hip_runtime.h>

// RecursiveRegression as banded-Toeplitz MFMA matmul, fused single kernel.
// y[i] = biasK + sum_{d=0}^{70} C[d]*h[i-d] (exact for i>=80; C = K conv
// rev(hwt); K = 64-tap impulse response of xwt feedback, |K[64]|~1e-5).
// mfma(Toeplitz, h_frag) orientation: TIME on D rows -> one dwordx4/lane store.
// Round 9: 8 half-strips/row-group (4096 blocks = 2 generations/CU) so
// generation-2 staging reads overlap generation-1 writes (round 8 was one
// generation: chip-wide read burst then write burst, never mixed).
// Nontemporal stores keep L2 clean for halo re-reads.
// Staging: waves 0-2. Setup: wave 3, lane-parallel K via shfl (hidden).
// Prefix i<80 (seed quirk, h[8] skipped) from LDS bf16 on strip-0 wave 0.

typedef float  f32x4  __attribute__((ext_vector_type(4)));
typedef short  bf16x8 __attribute__((ext_vector_type(8)));

#define TT 2048
#define BB 8192
#define LK 64
#define NTAPS 71
#define LROW 344   // shorts/row (336 used + 8 pad); stride 172 dwords

__device__ __forceinline__ unsigned f2bfu(float x) {   // RTN-even
    unsigned u = __float_as_uint(x);
    return (u + 0x7FFFu + ((u >> 16) & 1u)) >> 16;
}
__device__ __forceinline__ float bf2f(short s) {
    return __uint_as_float(((unsigned)(unsigned short)s) << 16);
}

__device__ __forceinline__ void group8(const float hwt[8], const float xwt[8],
                                       float bs, const float win[8],
                                       const float nh[8], const float xq[8],
                                       float res[8])
{
#pragma unroll
    for (int u = 0; u < 8; ++u) {
        float acc = bs;
#pragma unroll
        for (int k = u; k < 8; ++k) acc = fmaf(win[k], hwt[k - u], acc);
#pragma unroll
        for (int k = 0; k < u; ++k) acc = fmaf(nh[k], hwt[8 - u + k], acc);
#pragma unroll
        for (int k = u; k < 8; ++k) acc = fmaf(xq[k], xwt[k - u], acc);
#pragma unroll
        for (int k = 0; k < u; ++k) acc = fmaf(res[k], xwt[8 - u + k], acc);
        res[u] = acc;
    }
}

__global__ __launch_bounds__(256) void rr_fused(
    const float* __restrict__ h, const float* __restrict__ hwt_g,
    const float* __restrict__ xwt_g, const float* __restrict__ bias_g,
    float* __restrict__ out)
{
    __shared__ short hlds[16][LROW];     // 11,008 B
    __shared__ float kl[LK];
    __shared__ float cl[NTAPS + 1];

    const int t   = threadIdx.x;
    const int bid = blockIdx.x;
    const int s   = bid & 7;
    const int r0  = (bid >> 3) << 4;

    const int ts     = 5 + 16 * s;                 // first tile index
    const int ntiles = (s < 7) ? 16 : 11;          // tiles 5..116 / 117..127
    const int gcol0  = 256 * s;                    // = 16*ts - 80
    const int nf4    = (s < 7) ? 84 : 64;          // float4s staged per row

    if (t < 192) {
        // ---- staging: 12 threads per row, bf16 convert via v_cvt_pk ----
        const int row = t / 12;
        const int l12 = t - row * 12;
        const float* hrow = h + (size_t)(r0 + row) * TT + gcol0;
#pragma unroll
        for (int k = 0; k < 7; ++k) {
            const int c = l12 + 12 * k;
            if (c < nf4) {
                float4 v = reinterpret_cast<const float4*>(hrow)[c];
                uint2 pk;
                asm("v_cvt_pk_bf16_f32 %0, %1, %2" : "=v"(pk.x) : "v"(v.x), "v"(v.y));
                asm("v_cvt_pk_bf16_f32 %0, %1, %2" : "=v"(pk.y) : "v"(v.z), "v"(v.w));
                *reinterpret_cast<uint2*>(&hlds[row][4 * c]) = pk;
            }
        }
    } else {
        // ---- wave 3: lane-parallel setup (K recurrence + C taps) ----
        const int l = t - 192;                       // 0..63
        const float xw = (l < 8) ? xwt_g[l] : 0.f;   // lane j holds xwt[j]
        float w = 0.f, ksum = 0.f;                   // w = K[n-8+l], zero-padded
        for (int n = 0; n < LK; ++n) {
            float p = xw * w;                        // dot over 8-lane group
            p += __shfl_xor(p, 1);
            p += __shfl_xor(p, 2);
            p += __shfl_xor(p, 4);
            const float k = (n == 0) ? 1.f : p;
            ksum += k;
            if (l == 7) kl[n] = k;
            const float wshift = __shfl_down(w, 1);  // w[j] <- w[j+1]
            w = (l == 7) ? k : wshift;
        }
        if (l == 0) cl[NTAPS] = bias_g[0] * ksum;
        float hw[8];
#pragma unroll
        for (int j = 0; j < 8; ++j) hw[j] = hwt_g[j];
        // C[d] = sum_j hw[j]*K[d-7+j]; lanes cover d = l and d = l+64
#pragma unroll
        for (int pass = 0; pass < 2; ++pass) {
            const int d = l + 64 * pass;
            if (d < NTAPS) {
                float ca = 0.f;
#pragma unroll
                for (int j = 0; j < 8; ++j) {
                    const int n = d - 7 + j;
                    if (n >= 0 && n < LK) ca = fmaf(hw[j], kl[n], ca);
                }
                cl[d] = ca;
            }
        }
    }
    __syncthreads();

    const int lane = t & 63;
    const int v16  = lane & 15;     // Toeplitz-frag row (time); h-frag col (batch)
    const int gq   = lane >> 4;     // k-group; D row-quad (time-quad)
    const int w    = t >> 6;        // wave id

    const float biasK = cl[NTAPS];

    // ---- exact serial prefix i in [0,80) from LDS bf16: strip-0, wave 0 ----
    if (s == 0 && t < 16) {
        float* orow = out + (size_t)(r0 + t) * TT;
        float hwt[8], xwt[8];
#pragma unroll
        for (int j = 0; j < 8; ++j) { hwt[j] = hwt_g[j]; xwt[j] = xwt_g[j]; }
        const float bs = bias_g[0];
        float win[8], xq[8];
#pragma unroll
        for (int j = 0; j < 8; ++j) { win[j] = bf2f(hlds[t][j]); xq[j] = 0.f; }
        f32x4 z = {0.f, 0.f, 0.f, 0.f};
        __builtin_nontemporal_store(z, reinterpret_cast<f32x4*>(orow));
        __builtin_nontemporal_store(z, reinterpret_cast<f32x4*>(orow + 4));
        for (int g = 8; g < 80; g += 8) {     // appends h[g+1..g+8] (h[8] skipped)
            float nh[8], res[8];
#pragma unroll
            for (int j = 0; j < 8; ++j) nh[j] = bf2f(hlds[t][g + 1 + j]);
            group8(hwt, xwt, bs, win, nh, xq, res);
            f32x4 lo = {res[0], res[1], res[2], res[3]};
            f32x4 hi = {res[4], res[5], res[6], res[7]};
            __builtin_nontemporal_store(lo, reinterpret_cast<f32x4*>(orow + g));
            __builtin_nontemporal_store(hi, reinterpret_cast<f32x4*>(orow + g + 4));
#pragma unroll
            for (int j = 0; j < 8; ++j) { win[j] = nh[j]; xq[j] = res[j]; }
        }
    }

    // ---- Toeplitz fragments (A-operand): T'[v16][k] = C[80+v16-32kb-8gq-e] ----
    bf16x8 bfr[3];
#pragma unroll
    for (int kb = 0; kb < 3; ++kb) {
#pragma unroll
        for (int e = 0; e < 8; ++e) {
            const int idx = 80 + v16 - 32 * kb - 8 * gq - e;
            const float val = (idx >= 0 && idx < NTAPS) ? cl[idx] : 0.f;
            bfr[kb][e] = (short)f2bfu(val);
        }
    }

    // ---- tile loop: D^T orientation -> one dwordx4 nt-store per lane ----
    for (int tl = w; tl < ntiles; tl += 4) {
        const int colb = 16 * tl;
        f32x4 acc = {biasK, biasK, biasK, biasK};
#pragma unroll
        for (int kb = 0; kb < 3; ++kb) {
            const bf16x8 a = *reinterpret_cast<const bf16x8*>(
                &hlds[v16][colb + 32 * kb + 8 * gq]);
            // swapped operands: time on D rows, batch on D cols
            acc = __builtin_amdgcn_mfma_f32_16x16x32_bf16(bfr[kb], a, acc, 0, 0, 0);
        }
        const int i0 = (ts + tl) * 16;
        // lane (v16=batch, gq): out[r0+v16][i0+4gq .. +3] = acc[0..3]
        float* ob = out + (size_t)(r0 + v16) * TT + i0 + 4 * gq;
        __builtin_nontemporal_store(acc, reinterpret_cast<f32x4*>(ob));
    }
}

extern "C" void kernel_launch(void* const* d_in, const int* in_sizes, int n_in,
                              void* d_out, int out_size, void* d_ws, size_t ws_size,
                              hipStream_t stream) {
    const float* h    = (const float*)d_in[0];
    const float* hwt  = (const float*)d_in[1];
    const float* xwt  = (const float*)d_in[2];
    const float* bias = (const float*)d_in[3];
    float* out = (float*)d_out;
    rr_fused<<<(BB / 16) * 8, 256, 0, stream>>>(h, hwt, xwt, bias, out);
}

// Round 11
// 49.396 us; speedup vs baseline: 1.0826x; 1.0826x over previous
//
#include <hip/hip_runtime.h>

// RecursiveRegression as banded-Toeplitz MFMA matmul, fused single kernel.
// y[i] = biasK + sum_{d=0}^{70} C[d]*h[i-d] (exact for i>=80; C = K conv
// rev(hwt); K = 64-tap impulse response of xwt feedback, |K[64]|~1e-5).
// mfma(Toeplitz, h_frag) orientation: TIME on D rows -> one dwordx4/lane store.
// Round 11 = round 10 geometry (8 half-strips, 4096 blocks = 2 generations/CU
// so gen-2 staging reads overlap gen-1 writes) with NORMAL cached stores:
// round 10's nontemporal stores caused half-line writebacks (WRITE 65->88 MB,
// RMW amplification, 1.8x regression). L2 write-combining is load-bearing for
// this 64B-per-row scatter pattern.
// Staging: waves 0-2. Setup: wave 3, lane-parallel K via shfl (hidden).
// Prefix i<80 (seed quirk, h[8] skipped) from LDS bf16 on strip-0 wave 0.

typedef float  f32x4  __attribute__((ext_vector_type(4)));
typedef short  bf16x8 __attribute__((ext_vector_type(8)));

#define TT 2048
#define BB 8192
#define LK 64
#define NTAPS 71
#define LROW 344   // shorts/row (336 used + 8 pad); 172-dword stride -> 2-way (free)

__device__ __forceinline__ unsigned f2bfu(float x) {   // RTN-even
    unsigned u = __float_as_uint(x);
    return (u + 0x7FFFu + ((u >> 16) & 1u)) >> 16;
}
__device__ __forceinline__ float bf2f(short s) {
    return __uint_as_float(((unsigned)(unsigned short)s) << 16);
}

__device__ __forceinline__ void group8(const float hwt[8], const float xwt[8],
                                       float bs, const float win[8],
                                       const float nh[8], const float xq[8],
                                       float res[8])
{
#pragma unroll
    for (int u = 0; u < 8; ++u) {
        float acc = bs;
#pragma unroll
        for (int k = u; k < 8; ++k) acc = fmaf(win[k], hwt[k - u], acc);
#pragma unroll
        for (int k = 0; k < u; ++k) acc = fmaf(nh[k], hwt[8 - u + k], acc);
#pragma unroll
        for (int k = u; k < 8; ++k) acc = fmaf(xq[k], xwt[k - u], acc);
#pragma unroll
        for (int k = 0; k < u; ++k) acc = fmaf(res[k], xwt[8 - u + k], acc);
        res[u] = acc;
    }
}

__global__ __launch_bounds__(256) void rr_fused(
    const float* __restrict__ h, const float* __restrict__ hwt_g,
    const float* __restrict__ xwt_g, const float* __restrict__ bias_g,
    float* __restrict__ out)
{
    __shared__ short hlds[16][LROW];     // 11,008 B
    __shared__ float kl[LK];
    __shared__ float cl[NTAPS + 1];

    const int t   = threadIdx.x;
    const int bid = blockIdx.x;
    const int s   = bid & 7;
    const int r0  = (bid >> 3) << 4;

    const int ts     = 5 + 16 * s;                 // first tile index
    const int ntiles = (s < 7) ? 16 : 11;          // tiles 5..116 / 117..127
    const int gcol0  = 256 * s;                    // = 16*ts - 80
    const int nf4    = (s < 7) ? 84 : 64;          // float4s staged per row

    if (t < 192) {
        // ---- staging: 12 threads per row, bf16 convert via v_cvt_pk ----
        const int row = t / 12;
        const int l12 = t - row * 12;
        const float* hrow = h + (size_t)(r0 + row) * TT + gcol0;
#pragma unroll
        for (int k = 0; k < 7; ++k) {
            const int c = l12 + 12 * k;
            if (c < nf4) {
                float4 v = reinterpret_cast<const float4*>(hrow)[c];
                uint2 pk;
                asm("v_cvt_pk_bf16_f32 %0, %1, %2" : "=v"(pk.x) : "v"(v.x), "v"(v.y));
                asm("v_cvt_pk_bf16_f32 %0, %1, %2" : "=v"(pk.y) : "v"(v.z), "v"(v.w));
                *reinterpret_cast<uint2*>(&hlds[row][4 * c]) = pk;
            }
        }
    } else {
        // ---- wave 3: lane-parallel setup (K recurrence + C taps) ----
        const int l = t - 192;                       // 0..63
        const float xw = (l < 8) ? xwt_g[l] : 0.f;   // lane j holds xwt[j]
        float w = 0.f, ksum = 0.f;                   // w = K[n-8+l], zero-padded
        for (int n = 0; n < LK; ++n) {
            float p = xw * w;                        // dot over 8-lane group
            p += __shfl_xor(p, 1);
            p += __shfl_xor(p, 2);
            p += __shfl_xor(p, 4);
            const float k = (n == 0) ? 1.f : p;
            ksum += k;
            if (l == 7) kl[n] = k;
            const float wshift = __shfl_down(w, 1);  // w[j] <- w[j+1]
            w = (l == 7) ? k : wshift;
        }
        if (l == 0) cl[NTAPS] = bias_g[0] * ksum;
        float hw[8];
#pragma unroll
        for (int j = 0; j < 8; ++j) hw[j] = hwt_g[j];
        // C[d] = sum_j hw[j]*K[d-7+j]; lanes cover d = l and d = l+64
#pragma unroll
        for (int pass = 0; pass < 2; ++pass) {
            const int d = l + 64 * pass;
            if (d < NTAPS) {
                float ca = 0.f;
#pragma unroll
                for (int j = 0; j < 8; ++j) {
                    const int n = d - 7 + j;
                    if (n >= 0 && n < LK) ca = fmaf(hw[j], kl[n], ca);
                }
                cl[d] = ca;
            }
        }
    }
    __syncthreads();

    const int lane = t & 63;
    const int v16  = lane & 15;     // Toeplitz-frag row (time); h-frag col (batch)
    const int gq   = lane >> 4;     // k-group; D row-quad (time-quad)
    const int w    = t >> 6;        // wave id

    const float biasK = cl[NTAPS];

    // ---- exact serial prefix i in [0,80) from LDS bf16: strip-0, wave 0 ----
    if (s == 0 && t < 16) {
        float* orow = out + (size_t)(r0 + t) * TT;
        float hwt[8], xwt[8];
#pragma unroll
        for (int j = 0; j < 8; ++j) { hwt[j] = hwt_g[j]; xwt[j] = xwt_g[j]; }
        const float bs = bias_g[0];
        float win[8], xq[8];
#pragma unroll
        for (int j = 0; j < 8; ++j) { win[j] = bf2f(hlds[t][j]); xq[j] = 0.f; }
        float4 z = make_float4(0.f, 0.f, 0.f, 0.f);
        reinterpret_cast<float4*>(orow)[0] = z;
        reinterpret_cast<float4*>(orow)[1] = z;
        for (int g = 8; g < 80; g += 8) {     // appends h[g+1..g+8] (h[8] skipped)
            float nh[8], res[8];
#pragma unroll
            for (int j = 0; j < 8; ++j) nh[j] = bf2f(hlds[t][g + 1 + j]);
            group8(hwt, xwt, bs, win, nh, xq, res);
            float4* d4 = reinterpret_cast<float4*>(orow + g);
            d4[0] = make_float4(res[0], res[1], res[2], res[3]);
            d4[1] = make_float4(res[4], res[5], res[6], res[7]);
#pragma unroll
            for (int j = 0; j < 8; ++j) { win[j] = nh[j]; xq[j] = res[j]; }
        }
    }

    // ---- Toeplitz fragments (A-operand): T'[v16][k] = C[80+v16-32kb-8gq-e] ----
    bf16x8 bfr[3];
#pragma unroll
    for (int kb = 0; kb < 3; ++kb) {
#pragma unroll
        for (int e = 0; e < 8; ++e) {
            const int idx = 80 + v16 - 32 * kb - 8 * gq - e;
            const float val = (idx >= 0 && idx < NTAPS) ? cl[idx] : 0.f;
            bfr[kb][e] = (short)f2bfu(val);
        }
    }

    // ---- tile loop: D^T orientation -> one dwordx4 cached store per lane ----
    for (int tl = w; tl < ntiles; tl += 4) {
        const int colb = 16 * tl;
        f32x4 acc = {biasK, biasK, biasK, biasK};
#pragma unroll
        for (int kb = 0; kb < 3; ++kb) {
            const bf16x8 a = *reinterpret_cast<const bf16x8*>(
                &hlds[v16][colb + 32 * kb + 8 * gq]);
            // swapped operands: time on D rows, batch on D cols
            acc = __builtin_amdgcn_mfma_f32_16x16x32_bf16(bfr[kb], a, acc, 0, 0, 0);
        }
        const int i0 = (ts + tl) * 16;
        // lane (v16=batch, gq): out[r0+v16][i0+4gq .. +3] = acc[0..3]
        float* ob = out + (size_t)(r0 + v16) * TT + i0 + 4 * gq;
        *reinterpret_cast<f32x4*>(ob) = acc;
    }
}

extern "C" void kernel_launch(void* const* d_in, const int* in_sizes, int n_in,
                              void* d_out, int out_size, void* d_ws, size_t ws_size,
                              hipStream_t stream) {
    const float* h    = (const float*)d_in[0];
    const float* hwt  = (const float*)d_in[1];
    const float* xwt  = (const float*)d_in[2];
    const float* bias = (const float*)d_in[3];
    float* out = (float*)d_out;
    rr_fused<<<(BB / 16) * 8, 256, 0, stream>>>(h, hwt, xwt, bias, out);
}

// Round 12
// 29.067 us; speedup vs baseline: 1.8398x; 1.6994x over previous
//
#include <hip/hip_runtime.h>

// RecursiveRegression as banded-Toeplitz MFMA matmul, fused single kernel.
// y[i] = biasK + sum_{d=0}^{70} C[d]*h[i-d] (exact for i>=80; C = K conv
// rev(hwt); K = impulse response of xwt feedback, |K[64]|~1e-5).
// mfma(Toeplitz, h_frag) orientation: TIME on D rows -> one dwordx4/lane store.
// Round 12 = round-9 geometry (4 strips, 2048 blocks, cached stores; the
// 29.3 us config) + register-only setup: the old wave-3 shfl chain was
// 64 serial ds_bpermute round-trips (~12 us) on every block's barrier path
// (invisible to VALUBusy/MfmaUtil; exposed 2x by round 10/11's 2-generation
// grid). Now every lane runs the 72-step K recurrence redundantly in
// registers (~1.5 us pure VALU) and latches its C taps by predication:
// dsel_n = sum_j hw[j]*w[j] = C[n-1]; lane l takes n=l+1 -> C[l],
// n=l+65 -> C[l+64] (lanes 0..6).
// Staging: waves 0-2 (12 threads/row, v_cvt_pk bf16). Prefix i<80 (seed
// quirk, h[8] skipped) exact-structure from LDS bf16 on strip-0 wave 0.

typedef float  f32x4  __attribute__((ext_vector_type(4)));
typedef short  bf16x8 __attribute__((ext_vector_type(8)));

#define TT 2048
#define BB 8192
#define LK 64
#define NTAPS 71
#define LROW 584   // shorts/row = 1168 B; 292 dwords ≡ 4 mod 32 -> 2-way (free)

__device__ __forceinline__ unsigned f2bfu(float x) {   // RTN-even
    unsigned u = __float_as_uint(x);
    return (u + 0x7FFFu + ((u >> 16) & 1u)) >> 16;
}
__device__ __forceinline__ float bf2f(short s) {
    return __uint_as_float(((unsigned)(unsigned short)s) << 16);
}

__device__ __forceinline__ void group8(const float hwt[8], const float xwt[8],
                                       float bs, const float win[8],
                                       const float nh[8], const float xq[8],
                                       float res[8])
{
#pragma unroll
    for (int u = 0; u < 8; ++u) {
        float acc = bs;
#pragma unroll
        for (int k = u; k < 8; ++k) acc = fmaf(win[k], hwt[k - u], acc);
#pragma unroll
        for (int k = 0; k < u; ++k) acc = fmaf(nh[k], hwt[8 - u + k], acc);
#pragma unroll
        for (int k = u; k < 8; ++k) acc = fmaf(xq[k], xwt[k - u], acc);
#pragma unroll
        for (int k = 0; k < u; ++k) acc = fmaf(res[k], xwt[8 - u + k], acc);
        res[u] = acc;
    }
}

__global__ __launch_bounds__(256) void rr_fused(
    const float* __restrict__ h, const float* __restrict__ hwt_g,
    const float* __restrict__ xwt_g, const float* __restrict__ bias_g,
    float* __restrict__ out)
{
    __shared__ short hlds[16][LROW];     // 18,688 B
    __shared__ float cl[NTAPS + 1];

    const int t   = threadIdx.x;
    const int bid = blockIdx.x;
    const int s   = bid & 3;
    const int r0  = (bid >> 2) << 4;

    const int ts     = (s < 3) ? (5 + 31 * s) : 98;   // first tile index
    const int ntiles = (s < 3) ? 31 : 30;
    const int gcol0  = 16 * ts - 80;                  // 0,496,992,1488
    const int nf4    = (s < 3) ? 144 : 140;           // float4s staged per row

    if (t < 192) {
        // ---- staging: 12 threads per row, bf16 convert via v_cvt_pk ----
        const int row = t / 12;
        const int l12 = t - row * 12;
        const float* hrow = h + (size_t)(r0 + row) * TT + gcol0;
#pragma unroll 4
        for (int k = 0; k < 12; ++k) {
            const int c = l12 + 12 * k;
            if (c < nf4) {
                float4 v = reinterpret_cast<const float4*>(hrow)[c];
                uint2 pk;
                asm("v_cvt_pk_bf16_f32 %0, %1, %2" : "=v"(pk.x) : "v"(v.x), "v"(v.y));
                asm("v_cvt_pk_bf16_f32 %0, %1, %2" : "=v"(pk.y) : "v"(v.z), "v"(v.w));
                *reinterpret_cast<uint2*>(&hlds[row][4 * c]) = pk;
            }
        }
    } else {
        // ---- wave 3: register-only K/C setup (~1.5 us pure VALU) ----
        const int l = t - 192;                       // 0..63
        float xw[8], hw[8];
#pragma unroll
        for (int j = 0; j < 8; ++j) { xw[j] = xwt_g[j]; hw[j] = hwt_g[j]; }
        float w[8];                                  // w[j] = K[n-8+j], zero-padded
#pragma unroll
        for (int j = 0; j < 8; ++j) w[j] = 0.f;
        float c1 = 0.f, c2 = 0.f, ksum = 0.f;
        for (int n = 0; n <= NTAPS; ++n) {           // 72 iterations
            float dsel = 0.f;                        // = C[n-1]
#pragma unroll
            for (int j = 0; j < 8; ++j) dsel = fmaf(hw[j], w[j], dsel);
            if (n == l + 1)  c1 = dsel;              // C[l]
            if (n == l + 65) c2 = dsel;              // C[l+64], lanes 0..6
            float k = 0.f;
#pragma unroll
            for (int j = 0; j < 8; ++j) k = fmaf(xw[j], w[j], k);
            if (n == 0) k = 1.f;
            ksum += k;
#pragma unroll
            for (int j = 0; j < 7; ++j) w[j] = w[j + 1];
            w[7] = k;
        }
        cl[l] = c1;
        if (l < 7) cl[64 + l] = c2;
        if (l == 7) cl[NTAPS] = bias_g[0] * ksum;
    }
    __syncthreads();

    const int lane = t & 63;
    const int v16  = lane & 15;     // Toeplitz-frag row (time); h-frag col (batch)
    const int gq   = lane >> 4;     // k-group; D row-quad (time-quad)
    const int w    = t >> 6;        // wave id

    const float biasK = cl[NTAPS];

    // ---- exact serial prefix i in [0,80) from LDS bf16: strip-0, wave 0 ----
    if (s == 0 && t < 16) {
        float* orow = out + (size_t)(r0 + t) * TT;
        float hwt[8], xwt[8];
#pragma unroll
        for (int j = 0; j < 8; ++j) { hwt[j] = hwt_g[j]; xwt[j] = xwt_g[j]; }
        const float bs = bias_g[0];
        float win[8], xq[8];
#pragma unroll
        for (int j = 0; j < 8; ++j) { win[j] = bf2f(hlds[t][j]); xq[j] = 0.f; }
        float4 z = make_float4(0.f, 0.f, 0.f, 0.f);
        reinterpret_cast<float4*>(orow)[0] = z;
        reinterpret_cast<float4*>(orow)[1] = z;
        for (int g = 8; g < 80; g += 8) {     // appends h[g+1..g+8] (h[8] skipped)
            float nh[8], res[8];
#pragma unroll
            for (int j = 0; j < 8; ++j) nh[j] = bf2f(hlds[t][g + 1 + j]);
            group8(hwt, xwt, bs, win, nh, xq, res);
            float4* d4 = reinterpret_cast<float4*>(orow + g);
            d4[0] = make_float4(res[0], res[1], res[2], res[3]);
            d4[1] = make_float4(res[4], res[5], res[6], res[7]);
#pragma unroll
            for (int j = 0; j < 8; ++j) { win[j] = nh[j]; xq[j] = res[j]; }
        }
    }

    // ---- Toeplitz fragments (A-operand): T'[v16][k] = C[80+v16-32kb-8gq-e] ----
    bf16x8 bfr[3];
#pragma unroll
    for (int kb = 0; kb < 3; ++kb) {
#pragma unroll
        for (int e = 0; e < 8; ++e) {
            const int idx = 80 + v16 - 32 * kb - 8 * gq - e;
            const float val = (idx >= 0 && idx < NTAPS) ? cl[idx] : 0.f;
            bfr[kb][e] = (short)f2bfu(val);
        }
    }

    // ---- tile loop: D^T orientation -> one dwordx4 cached store per lane ----
    for (int tl = w; tl < ntiles; tl += 4) {
        const int colb = 16 * tl;
        f32x4 acc = {biasK, biasK, biasK, biasK};
#pragma unroll
        for (int kb = 0; kb < 3; ++kb) {
            const bf16x8 a = *reinterpret_cast<const bf16x8*>(
                &hlds[v16][colb + 32 * kb + 8 * gq]);
            // swapped operands: time on D rows, batch on D cols
            acc = __builtin_amdgcn_mfma_f32_16x16x32_bf16(bfr[kb], a, acc, 0, 0, 0);
        }
        const int i0 = (ts + tl) * 16;
        // lane (v16=batch, gq): out[r0+v16][i0+4gq .. +3] = acc[0..3]
        float* ob = out + (size_t)(r0 + v16) * TT + i0 + 4 * gq;
        *reinterpret_cast<f32x4*>(ob) = acc;
    }
}

extern "C" void kernel_launch(void* const* d_in, const int* in_sizes, int n_in,
                              void* d_out, int out_size, void* d_ws, size_t ws_size,
                              hipStream_t stream) {
    const float* h    = (const float*)d_in[0];
    const float* hwt  = (const float*)d_in[1];
    const float* xwt  = (const float*)d_in[2];
    const float* bias = (const float*)d_in[3];
    float* out = (float*)d_out;
    rr_fused<<<(BB / 16) * 4, 256, 0, stream>>>(h, hwt, xwt, bias, out);
}